// Round 21
// baseline (120.157 us; speedup 1.0000x reference)
//
#include <hip/hip_runtime.h>

#define TOTAL     4194304
#define DIM       32
#define NTOK      (TOTAL / DIM)   // 131072 tokens
#define NCODE     1024
#define CCODES    256             // codes per chunk (4 chunks) -- proven R5/R18 geometry
#define DELTA_EPS 2e-3f
#define FLAGBIT   0x40000000

typedef _Float16 half8   __attribute__((ext_vector_type(8)));
typedef float    floatx4 __attribute__((ext_vector_type(4)));

#define GLOAD_LDS16(g, l) \
    __builtin_amdgcn_global_load_lds((const __attribute__((address_space(1))) void*)(g), \
                                     (__attribute__((address_space(3))) void*)(l), 16, 0, 0)
#define GLOAD_LDS4(g, l) \
    __builtin_amdgcn_global_load_lds((const __attribute__((address_space(1))) void*)(g), \
                                     (__attribute__((address_space(3))) void*)(l), 4, 0, 0)

// ---------------- prep: codebook -> f16 hi/lo fragments + (-0.5*|e|^2) + TRANSPOSE ------
// Fragment slot for code k (256-code chunks): chunk=k>>8, step=(k&255)>>4, l15=k&15;
// slot = chunk*1024 + step*64 + l4*16 + l15 (8 halves = 16 B per slot).
// cbT[j][k] = cb[k][j] (dim-major fp32) -> rescore reads become lane-coalesced.
__global__ __launch_bounds__(64) void vq_prep(
    const float* __restrict__ cb, float* __restrict__ nhb,
    _Float16* __restrict__ Eh, _Float16* __restrict__ El,
    float* __restrict__ cbT)
{
    const int k = blockIdx.x * 64 + threadIdx.x;   // code id
    const float4* e4 = reinterpret_cast<const float4*>(cb) + (size_t)k * 8;
    float v[DIM];
    float4 t[8];
#pragma unroll
    for (int j = 0; j < 8; ++j) t[j] = e4[j];
#pragma unroll
    for (int j = 0; j < 8; ++j) {
        v[4 * j + 0] = t[j].x; v[4 * j + 1] = t[j].y;
        v[4 * j + 2] = t[j].z; v[4 * j + 3] = t[j].w;
    }
    float e2 = 0.0f;
#pragma unroll
    for (int i = 0; i < DIM; ++i) e2 = fmaf(v[i], v[i], e2);   // sequential: matches rescore
    nhb[k] = -0.5f * e2;

    // transpose: for fixed j, lanes write consecutive k -> coalesced 256 B stores
#pragma unroll
    for (int j = 0; j < DIM; ++j) cbT[(size_t)j * NCODE + k] = v[j];

    const int chunk = k >> 8, within = k & 255;
    const int step = within >> 4, l15 = within & 15;
#pragma unroll
    for (int l4 = 0; l4 < 4; ++l4) {
        half8 h, lo;
#pragma unroll
        for (int j = 0; j < 8; ++j) {
            float x = v[l4 * 8 + j];
            _Float16 hh = (_Float16)x;
            h[j]  = hh;
            lo[j] = (_Float16)(x - (float)hh);
        }
        const int slot = chunk * 1024 + step * 64 + l4 * 16 + l15;
        *reinterpret_cast<half8*>(Eh + (size_t)slot * 8) = h;
        *reinterpret_cast<half8*>(El + (size_t)slot * 8) = lo;
    }
}

// ---------------- main: R5-proven MFMA argmax + coalesced fused exact rescore ----------
// 1024 blocks x 256 thr; wave owns 32 tokens (m=2); 4 chunks x 256 codes; LDS ~34.5 KB.
// Rescore streams the TRANSPOSED codebook (lane-coalesced dword loads, L2-resident).
__global__ __launch_bounds__(256) void vq_main(
    const float* __restrict__ w, const float* __restrict__ c,
    const float* __restrict__ nhb, const _Float16* __restrict__ Eh,
    const _Float16* __restrict__ El, const float* __restrict__ cbT,
    int* __restrict__ out)
{
    __shared__ _Float16 sEh[1024 * 8];   // 16 KB: [step(16)][lane(64)][8 halves]
    __shared__ _Float16 sEl[1024 * 8];   // 16 KB
    __shared__ float    snh[CCODES];     // 1 KB
    __shared__ int      sOut[128];       // 512 B
    __shared__ float    sXf[4][DIM];     // 512 B per-wave rescore scratch

    const int tid  = threadIdx.x;
    const int lane = tid & 63;
    const int wid  = tid >> 6;
    const int tokw = blockIdx.x * 128 + wid * 32;   // 32 tokens per wave
    const int l15  = lane & 15;
    const int l4   = lane >> 4;

    // A fragments: 2 tiles of 16 tokens. A[row=l15][k=l4*8+j]; exact x = xh + xl
    half8 xh[2], xl[2];
#pragma unroll
    for (int m = 0; m < 2; ++m) {
        const int token = tokw + m * 16 + l15;
        const float4* pw = reinterpret_cast<const float4*>(w + (size_t)token * DIM + l4 * 8);
        const float4* pc = reinterpret_cast<const float4*>(c + (size_t)token * DIM + l4 * 8);
        float4 a0 = pw[0], a1 = pw[1], b0 = pc[0], b1 = pc[1];
        float xs[8] = {a0.x - b0.x, a0.y - b0.y, a0.z - b0.z, a0.w - b0.w,
                       a1.x - b1.x, a1.y - b1.y, a1.z - b1.z, a1.w - b1.w};
#pragma unroll
        for (int j = 0; j < 8; ++j) {
            _Float16 h = (_Float16)xs[j];
            xh[m][j] = h;
            xl[m][j] = (_Float16)(xs[j] - (float)h);
        }
    }

    const float NEGINF = __uint_as_float(0xFF800000u);
    float best[8], second[8];
#pragma unroll
    for (int q = 0; q < 8; ++q) { best[q] = NEGINF; second[q] = NEGINF; }

    for (int ch = 0; ch < 4; ++ch) {
        if (ch) __syncthreads();   // all waves done reading previous chunk before overwrite
        {   // stage 256 codes (hi+lo, 32 KB) + snh (1 KB), all-linear async global->LDS
            const _Float16* gh = Eh + (size_t)ch * 8192;
            const _Float16* gl = El + (size_t)ch * 8192;
#pragma unroll
            for (int r2 = 0; r2 < 4; ++r2) {
                const int slot = r2 * 256 + wid * 64;   // wave-uniform base
                GLOAD_LDS16(gh + (size_t)(slot + lane) * 8, sEh + (size_t)slot * 8);
                GLOAD_LDS16(gl + (size_t)(slot + lane) * 8, sEl + (size_t)slot * 8);
            }
            GLOAD_LDS4(nhb + ch * CCODES + wid * 64 + lane, snh + wid * 64);
        }
        __syncthreads();   // drain -> staged data visible

        // 16 steps of 16 codes, in pairs (med3 second-tracking) -- R5's proven loop
#pragma unroll
        for (int sp = 0; sp < 8; ++sp) {
            const int sA = 2 * sp, sB = 2 * sp + 1;
            const half8 ehA = *reinterpret_cast<const half8*>(sEh + (size_t)(sA * 64 + lane) * 8);
            const half8 elA = *reinterpret_cast<const half8*>(sEl + (size_t)(sA * 64 + lane) * 8);
            const half8 ehB = *reinterpret_cast<const half8*>(sEh + (size_t)(sB * 64 + lane) * 8);
            const half8 elB = *reinterpret_cast<const half8*>(sEl + (size_t)(sB * 64 + lane) * 8);
            const float nhA = snh[sA * 16 + l15];
            const float nhB = snh[sB * 16 + l15];
            const unsigned ixA = 1023u - (unsigned)(ch * CCODES + sA * 16 + l15);
            const unsigned ixB = ixA - 16u;
            const floatx4 nA = {nhA, nhA, nhA, nhA};
            const floatx4 nB = {nhB, nhB, nhB, nhB};
#pragma unroll
            for (int m = 0; m < 2; ++m) {
                floatx4 aA = __builtin_amdgcn_mfma_f32_16x16x32_f16(xh[m], ehA, nA, 0, 0, 0);
                aA = __builtin_amdgcn_mfma_f32_16x16x32_f16(xl[m], ehA, aA, 0, 0, 0);
                aA = __builtin_amdgcn_mfma_f32_16x16x32_f16(xh[m], elA, aA, 0, 0, 0);
                floatx4 aB = __builtin_amdgcn_mfma_f32_16x16x32_f16(xh[m], ehB, nB, 0, 0, 0);
                aB = __builtin_amdgcn_mfma_f32_16x16x32_f16(xl[m], ehB, aB, 0, 0, 0);
                aB = __builtin_amdgcn_mfma_f32_16x16x32_f16(xh[m], elB, aB, 0, 0, 0);
#pragma unroll
                for (int r = 0; r < 4; ++r) {
                    const int q = m * 4 + r;
                    float pA = __uint_as_float((__float_as_uint(aA[r]) & 0xFFFFFC00u) | ixA);
                    float pB = __uint_as_float((__float_as_uint(aB[r]) & 0xFFFFFC00u) | ixB);
                    second[q] = fmaxf(second[q], __builtin_amdgcn_fmed3f(pA, pB, best[q]));
                    best[q]   = fmaxf(fmaxf(best[q], pA), pB);
                }
            }
        }
    }

    // reduce across the 16 code-lanes (xor over lane bits 0..3)
#pragma unroll
    for (int sh = 1; sh < 16; sh <<= 1) {
#pragma unroll
        for (int q = 0; q < 8; ++q) {
            float bB = __shfl_xor(best[q], sh);
            float sB = __shfl_xor(second[q], sh);
            second[q] = fmaxf(fmaxf(second[q], sB), fminf(best[q], bB));
            best[q]   = fmaxf(best[q], bB);
        }
    }

    // stage per-token results (k | optional FLAGBIT) -- R12's proven threshold
    if (l15 == 0) {
#pragma unroll
        for (int m = 0; m < 2; ++m) {
#pragma unroll
            for (int r = 0; r < 4; ++r) {
                const int q = m * 4 + r;
                unsigned ub = __float_as_uint(best[q]);
                unsigned us = __float_as_uint(second[q]);
                float bv = __uint_as_float(ub & 0xFFFFFC00u);
                float sv = __uint_as_float(us & 0xFFFFFC00u);
                int eb = (int)((ub >> 23) & 255u);
                int es = (int)((us >> 23) & 255u);
                int em = eb > es ? eb : es;
                em = em > 12 ? em : 12;
                // flag threshold = 4 * packing granule + eps (covers split-f16 error)
                float thr = __uint_as_float((unsigned)(em - 11) << 23) + DELTA_EPS;
                int k = 1023 - (int)(ub & 1023u);
                sOut[wid * 32 + m * 16 + l4 * 4 + r] = ((bv - sv) < thr) ? (k | FLAGBIT) : k;
            }
        }
    }

    // lane i (<32) owns token tokw+i; rescore flagged tokens exactly (wave-cooperative).
    // COALESCED path: x staged in per-wave LDS (broadcast reads); codebook read from the
    // dim-major transpose -> for fixed j, lanes hit consecutive dwords (256 B/instr, L2).
    // Same sequential-fma order (j = 0..31) -> bit-identical to the proven rescore.
    int myval = 0;
    if (lane < 32) myval = sOut[wid * 32 + lane];
    unsigned long long mask = __ballot(lane < 32 && (myval & FLAGBIT));
    while (mask) {
        const int src = __ffsll(mask) - 1;
        mask &= mask - 1;
        const int token = tokw + src;   // wave-uniform

        if (lane < DIM)
            sXf[wid][lane] = w[(size_t)token * DIM + lane] - c[(size_t)token * DIM + lane];
        // LDS ops within a wave complete in order; compiler inserts lgkmcnt before reads.

        float x2 = 0.f;
#pragma unroll
        for (int i = 0; i < DIM; ++i) x2 = fmaf(sXf[wid][i], sXf[wid][i], x2);

        float dmin = INFINITY;
        int   kbest = 0;
#pragma unroll
        for (int i = 0; i < 16; ++i) {
            const int k = lane + 64 * i;           // ascending per lane
            float dot = 0.f;
#pragma unroll
            for (int j = 0; j < DIM; ++j)          // sequential order j=0..31
                dot = fmaf(sXf[wid][j], cbT[(size_t)j * NCODE + k], dot);
            float e2 = -2.0f * nhb[k];             // bit-exact |e|^2 (seq-fma in prep)
            float dd = fmaf(-2.0f, dot, x2) + e2;
            if (dd < dmin) { dmin = dd; kbest = k; }
        }
#pragma unroll
        for (int sh = 1; sh < 64; sh <<= 1) {
            float dB = __shfl_xor(dmin, sh);
            int   iB = __shfl_xor(kbest, sh);
            bool take = (dB < dmin) || (dB == dmin && iB < kbest);
            dmin = take ? dB : dmin;
            kbest = take ? iB : kbest;
        }
        if (lane == src) myval = kbest;   // exact index, flag cleared
    }
    if (lane < 32) out[tokw + lane] = myval;   // coalesced 128 B per wave
}

extern "C" void kernel_launch(void* const* d_in, const int* in_sizes, int n_in,
                              void* d_out, int out_size, void* d_ws, size_t ws_size,
                              hipStream_t stream) {
    const float* w  = (const float*)d_in[0];   // weights   [4194304]
    const float* c  = (const float*)d_in[1];   // condition [1,32,131072] flat
    const float* cb = (const float*)d_in[2];   // codebook  [1024,32]
    int* out = (int*)d_out;                    // int32 indices [131072]

    char* wsb = (char*)d_ws;
    float*    nhb = (float*)wsb;                                // 4 KB
    _Float16* Eh  = (_Float16*)(wsb + 4096);                    // 64 KB (fragment-ordered)
    _Float16* El  = (_Float16*)(wsb + 4096 + 65536);            // 64 KB (fragment-ordered)
    float*    cbT = (float*)(wsb + 4096 + 65536 + 65536);       // 128 KB (dim-major)

    vq_prep<<<NCODE / 64, 64, 0, stream>>>(cb, nhb, Eh, El, cbT);
    vq_main<<<NTOK / 128, 256, 0, stream>>>(w, c, nhb, Eh, El, cbT, out);
}

// Round 22
// 55.876 us; speedup vs baseline: 2.1504x; 2.1504x over previous
//
#include <hip/hip_runtime.h>

#define TOTAL     4194304
#define DIM       32
#define NTOK      (TOTAL / DIM)   // 131072 tokens
#define NCODE     1024
#define CCODES    256             // codes per chunk (4 chunks) -- proven R5/R18 geometry
#define DELTA_EPS 2e-3f
#define FLAGBIT   0x40000000

typedef _Float16 half8   __attribute__((ext_vector_type(8)));
typedef float    floatx4 __attribute__((ext_vector_type(4)));

#define GLOAD_LDS16(g, l) \
    __builtin_amdgcn_global_load_lds((const __attribute__((address_space(1))) void*)(g), \
                                     (__attribute__((address_space(3))) void*)(l), 16, 0, 0)
#define GLOAD_LDS4(g, l) \
    __builtin_amdgcn_global_load_lds((const __attribute__((address_space(1))) void*)(g), \
                                     (__attribute__((address_space(3))) void*)(l), 4, 0, 0)

// ---------------- prep: codebook -> f16 hi/lo fragments + (-0.5*|e|^2) + TRANSPOSE ------
// Fragment slot for code k (256-code chunks): chunk=k>>8, step=(k&255)>>4, l15=k&15;
// slot = chunk*1024 + step*64 + l4*16 + l15 (8 halves = 16 B per slot).
// cbT[j][k] = cb[k][j] (dim-major fp32) -> rescore reads become lane-coalesced.
__global__ __launch_bounds__(64) void vq_prep(
    const float* __restrict__ cb, float* __restrict__ nhb,
    _Float16* __restrict__ Eh, _Float16* __restrict__ El,
    float* __restrict__ cbT)
{
    const int k = blockIdx.x * 64 + threadIdx.x;   // code id
    const float4* e4 = reinterpret_cast<const float4*>(cb) + (size_t)k * 8;
    float v[DIM];
    float4 t[8];
#pragma unroll
    for (int j = 0; j < 8; ++j) t[j] = e4[j];
#pragma unroll
    for (int j = 0; j < 8; ++j) {
        v[4 * j + 0] = t[j].x; v[4 * j + 1] = t[j].y;
        v[4 * j + 2] = t[j].z; v[4 * j + 3] = t[j].w;
    }
    float e2 = 0.0f;
#pragma unroll
    for (int i = 0; i < DIM; ++i) e2 = fmaf(v[i], v[i], e2);   // sequential: matches rescore
    nhb[k] = -0.5f * e2;

    // transpose: for fixed j, lanes write consecutive k -> coalesced 256 B stores
#pragma unroll
    for (int j = 0; j < DIM; ++j) cbT[(size_t)j * NCODE + k] = v[j];

    const int chunk = k >> 8, within = k & 255;
    const int step = within >> 4, l15 = within & 15;
#pragma unroll
    for (int l4 = 0; l4 < 4; ++l4) {
        half8 h, lo;
#pragma unroll
        for (int j = 0; j < 8; ++j) {
            float x = v[l4 * 8 + j];
            _Float16 hh = (_Float16)x;
            h[j]  = hh;
            lo[j] = (_Float16)(x - (float)hh);
        }
        const int slot = chunk * 1024 + step * 64 + l4 * 16 + l15;
        *reinterpret_cast<half8*>(Eh + (size_t)slot * 8) = h;
        *reinterpret_cast<half8*>(El + (size_t)slot * 8) = lo;
    }
}

// ---------------- main: R5-proven MFMA argmax + coalesced fused exact rescore ----------
// 1024 blocks x 256 thr; wave owns 32 tokens (m=2); 4 chunks x 256 codes; LDS ~34.5 KB.
// Rescore streams the TRANSPOSED codebook (lane-coalesced dword loads, L2-resident).
// NOTE: rescore i-loop deliberately NOT unrolled (R21 lesson: full unroll -> VGPR 256).
__global__ __launch_bounds__(256) void vq_main(
    const float* __restrict__ w, const float* __restrict__ c,
    const float* __restrict__ nhb, const _Float16* __restrict__ Eh,
    const _Float16* __restrict__ El, const float* __restrict__ cbT,
    int* __restrict__ out)
{
    __shared__ _Float16 sEh[1024 * 8];   // 16 KB: [step(16)][lane(64)][8 halves]
    __shared__ _Float16 sEl[1024 * 8];   // 16 KB
    __shared__ float    snh[CCODES];     // 1 KB
    __shared__ int      sOut[128];       // 512 B
    __shared__ float    sXf[4][DIM];     // 512 B per-wave rescore scratch

    const int tid  = threadIdx.x;
    const int lane = tid & 63;
    const int wid  = tid >> 6;
    const int tokw = blockIdx.x * 128 + wid * 32;   // 32 tokens per wave
    const int l15  = lane & 15;
    const int l4   = lane >> 4;

    // A fragments: 2 tiles of 16 tokens. A[row=l15][k=l4*8+j]; exact x = xh + xl
    half8 xh[2], xl[2];
#pragma unroll
    for (int m = 0; m < 2; ++m) {
        const int token = tokw + m * 16 + l15;
        const float4* pw = reinterpret_cast<const float4*>(w + (size_t)token * DIM + l4 * 8);
        const float4* pc = reinterpret_cast<const float4*>(c + (size_t)token * DIM + l4 * 8);
        float4 a0 = pw[0], a1 = pw[1], b0 = pc[0], b1 = pc[1];
        float xs[8] = {a0.x - b0.x, a0.y - b0.y, a0.z - b0.z, a0.w - b0.w,
                       a1.x - b1.x, a1.y - b1.y, a1.z - b1.z, a1.w - b1.w};
#pragma unroll
        for (int j = 0; j < 8; ++j) {
            _Float16 h = (_Float16)xs[j];
            xh[m][j] = h;
            xl[m][j] = (_Float16)(xs[j] - (float)h);
        }
    }

    const float NEGINF = __uint_as_float(0xFF800000u);
    float best[8], second[8];
#pragma unroll
    for (int q = 0; q < 8; ++q) { best[q] = NEGINF; second[q] = NEGINF; }

    for (int ch = 0; ch < 4; ++ch) {
        if (ch) __syncthreads();   // all waves done reading previous chunk before overwrite
        {   // stage 256 codes (hi+lo, 32 KB) + snh (1 KB), all-linear async global->LDS
            const _Float16* gh = Eh + (size_t)ch * 8192;
            const _Float16* gl = El + (size_t)ch * 8192;
#pragma unroll
            for (int r2 = 0; r2 < 4; ++r2) {
                const int slot = r2 * 256 + wid * 64;   // wave-uniform base
                GLOAD_LDS16(gh + (size_t)(slot + lane) * 8, sEh + (size_t)slot * 8);
                GLOAD_LDS16(gl + (size_t)(slot + lane) * 8, sEl + (size_t)slot * 8);
            }
            GLOAD_LDS4(nhb + ch * CCODES + wid * 64 + lane, snh + wid * 64);
        }
        __syncthreads();   // drain -> staged data visible

        // 16 steps of 16 codes, in pairs (med3 second-tracking) -- R5's proven loop
#pragma unroll
        for (int sp = 0; sp < 8; ++sp) {
            const int sA = 2 * sp, sB = 2 * sp + 1;
            const half8 ehA = *reinterpret_cast<const half8*>(sEh + (size_t)(sA * 64 + lane) * 8);
            const half8 elA = *reinterpret_cast<const half8*>(sEl + (size_t)(sA * 64 + lane) * 8);
            const half8 ehB = *reinterpret_cast<const half8*>(sEh + (size_t)(sB * 64 + lane) * 8);
            const half8 elB = *reinterpret_cast<const half8*>(sEl + (size_t)(sB * 64 + lane) * 8);
            const float nhA = snh[sA * 16 + l15];
            const float nhB = snh[sB * 16 + l15];
            const unsigned ixA = 1023u - (unsigned)(ch * CCODES + sA * 16 + l15);
            const unsigned ixB = ixA - 16u;
            const floatx4 nA = {nhA, nhA, nhA, nhA};
            const floatx4 nB = {nhB, nhB, nhB, nhB};
#pragma unroll
            for (int m = 0; m < 2; ++m) {
                floatx4 aA = __builtin_amdgcn_mfma_f32_16x16x32_f16(xh[m], ehA, nA, 0, 0, 0);
                aA = __builtin_amdgcn_mfma_f32_16x16x32_f16(xl[m], ehA, aA, 0, 0, 0);
                aA = __builtin_amdgcn_mfma_f32_16x16x32_f16(xh[m], elA, aA, 0, 0, 0);
                floatx4 aB = __builtin_amdgcn_mfma_f32_16x16x32_f16(xh[m], ehB, nB, 0, 0, 0);
                aB = __builtin_amdgcn_mfma_f32_16x16x32_f16(xl[m], ehB, aB, 0, 0, 0);
                aB = __builtin_amdgcn_mfma_f32_16x16x32_f16(xh[m], elB, aB, 0, 0, 0);
#pragma unroll
                for (int r = 0; r < 4; ++r) {
                    const int q = m * 4 + r;
                    float pA = __uint_as_float((__float_as_uint(aA[r]) & 0xFFFFFC00u) | ixA);
                    float pB = __uint_as_float((__float_as_uint(aB[r]) & 0xFFFFFC00u) | ixB);
                    second[q] = fmaxf(second[q], __builtin_amdgcn_fmed3f(pA, pB, best[q]));
                    best[q]   = fmaxf(fmaxf(best[q], pA), pB);
                }
            }
        }
    }

    // reduce across the 16 code-lanes (xor over lane bits 0..3)
#pragma unroll
    for (int sh = 1; sh < 16; sh <<= 1) {
#pragma unroll
        for (int q = 0; q < 8; ++q) {
            float bB = __shfl_xor(best[q], sh);
            float sB = __shfl_xor(second[q], sh);
            second[q] = fmaxf(fmaxf(second[q], sB), fminf(best[q], bB));
            best[q]   = fmaxf(best[q], bB);
        }
    }

    // stage per-token results (k | optional FLAGBIT) -- R12's proven threshold
    if (l15 == 0) {
#pragma unroll
        for (int m = 0; m < 2; ++m) {
#pragma unroll
            for (int r = 0; r < 4; ++r) {
                const int q = m * 4 + r;
                unsigned ub = __float_as_uint(best[q]);
                unsigned us = __float_as_uint(second[q]);
                float bv = __uint_as_float(ub & 0xFFFFFC00u);
                float sv = __uint_as_float(us & 0xFFFFFC00u);
                int eb = (int)((ub >> 23) & 255u);
                int es = (int)((us >> 23) & 255u);
                int em = eb > es ? eb : es;
                em = em > 12 ? em : 12;
                // flag threshold = 4 * packing granule + eps (covers split-f16 error)
                float thr = __uint_as_float((unsigned)(em - 11) << 23) + DELTA_EPS;
                int k = 1023 - (int)(ub & 1023u);
                sOut[wid * 32 + m * 16 + l4 * 4 + r] = ((bv - sv) < thr) ? (k | FLAGBIT) : k;
            }
        }
    }

    // lane i (<32) owns token tokw+i; rescore flagged tokens exactly (wave-cooperative).
    // COALESCED path: x staged in per-wave LDS (broadcast reads); codebook read from the
    // dim-major transpose -> for fixed j, lanes hit consecutive dwords (256 B/instr, L2).
    // Same sequential-fma order (j = 0..31) -> bit-identical to the proven rescore.
    int myval = 0;
    if (lane < 32) myval = sOut[wid * 32 + lane];
    unsigned long long mask = __ballot(lane < 32 && (myval & FLAGBIT));
    while (mask) {
        const int src = __ffsll(mask) - 1;
        mask &= mask - 1;
        const int token = tokw + src;   // wave-uniform

        if (lane < DIM)
            sXf[wid][lane] = w[(size_t)token * DIM + lane] - c[(size_t)token * DIM + lane];
        // LDS ops within a wave complete in order; compiler inserts lgkmcnt before reads.

        float x2 = 0.f;
#pragma unroll
        for (int i = 0; i < DIM; ++i) x2 = fmaf(sXf[wid][i], sXf[wid][i], x2);

        float dmin = INFINITY;
        int   kbest = 0;
        for (int i = 0; i < 16; ++i) {             // NOT unrolled (R21: unroll -> VGPR 256)
            const int k = lane + 64 * i;           // ascending per lane
            float dot = 0.f;
#pragma unroll
            for (int j = 0; j < DIM; ++j)          // sequential order j=0..31
                dot = fmaf(sXf[wid][j], cbT[(size_t)j * NCODE + k], dot);
            float e2 = -2.0f * nhb[k];             // bit-exact |e|^2 (seq-fma in prep)
            float dd = fmaf(-2.0f, dot, x2) + e2;
            if (dd < dmin) { dmin = dd; kbest = k; }
        }
#pragma unroll
        for (int sh = 1; sh < 64; sh <<= 1) {
            float dB = __shfl_xor(dmin, sh);
            int   iB = __shfl_xor(kbest, sh);
            bool take = (dB < dmin) || (dB == dmin && iB < kbest);
            dmin = take ? dB : dmin;
            kbest = take ? iB : kbest;
        }
        if (lane == src) myval = kbest;   // exact index, flag cleared
    }
    if (lane < 32) out[tokw + lane] = myval;   // coalesced 128 B per wave
}

extern "C" void kernel_launch(void* const* d_in, const int* in_sizes, int n_in,
                              void* d_out, int out_size, void* d_ws, size_t ws_size,
                              hipStream_t stream) {
    const float* w  = (const float*)d_in[0];   // weights   [4194304]
    const float* c  = (const float*)d_in[1];   // condition [1,32,131072] flat
    const float* cb = (const float*)d_in[2];   // codebook  [1024,32]
    int* out = (int*)d_out;                    // int32 indices [131072]

    char* wsb = (char*)d_ws;
    float*    nhb = (float*)wsb;                                // 4 KB
    _Float16* Eh  = (_Float16*)(wsb + 4096);                    // 64 KB (fragment-ordered)
    _Float16* El  = (_Float16*)(wsb + 4096 + 65536);            // 64 KB (fragment-ordered)
    float*    cbT = (float*)(wsb + 4096 + 65536 + 65536);       // 128 KB (dim-major)

    vq_prep<<<NCODE / 64, 64, 0, stream>>>(cb, nhb, Eh, El, cbT);
    vq_main<<<NTOK / 128, 256, 0, stream>>>(w, c, nhb, Eh, El, cbT, out);
}

// Round 23
// 52.699 us; speedup vs baseline: 2.2801x; 1.0603x over previous
//
#include <hip/hip_runtime.h>

#define TOTAL     4194304
#define DIM       32
#define NTOK      (TOTAL / DIM)   // 131072 tokens
#define NCODE     1024
#define CCODES    256             // codes per chunk (4 chunks) -- proven R5/R18 geometry
#define DELTA_EPS 2e-3f
#define FLAGBIT   0x40000000

typedef _Float16 half8   __attribute__((ext_vector_type(8)));
typedef float    floatx4 __attribute__((ext_vector_type(4)));

#define GLOAD_LDS16(g, l) \
    __builtin_amdgcn_global_load_lds((const __attribute__((address_space(1))) void*)(g), \
                                     (__attribute__((address_space(3))) void*)(l), 16, 0, 0)
#define GLOAD_LDS4(g, l) \
    __builtin_amdgcn_global_load_lds((const __attribute__((address_space(1))) void*)(g), \
                                     (__attribute__((address_space(3))) void*)(l), 4, 0, 0)

// ---------------- prep: codebook -> f16 hi/lo fragments + (-0.5*|e|^2) + TRANSPOSE ------
__global__ __launch_bounds__(64) void vq_prep(
    const float* __restrict__ cb, float* __restrict__ nhb,
    _Float16* __restrict__ Eh, _Float16* __restrict__ El,
    float* __restrict__ cbT)
{
    const int k = blockIdx.x * 64 + threadIdx.x;   // code id
    const float4* e4 = reinterpret_cast<const float4*>(cb) + (size_t)k * 8;
    float v[DIM];
    float4 t[8];
#pragma unroll
    for (int j = 0; j < 8; ++j) t[j] = e4[j];
#pragma unroll
    for (int j = 0; j < 8; ++j) {
        v[4 * j + 0] = t[j].x; v[4 * j + 1] = t[j].y;
        v[4 * j + 2] = t[j].z; v[4 * j + 3] = t[j].w;
    }
    float e2 = 0.0f;
#pragma unroll
    for (int i = 0; i < DIM; ++i) e2 = fmaf(v[i], v[i], e2);   // sequential: matches rescore
    nhb[k] = -0.5f * e2;

    // transpose: for fixed j, lanes write consecutive k -> coalesced stores
#pragma unroll
    for (int j = 0; j < DIM; ++j) cbT[(size_t)j * NCODE + k] = v[j];

    const int chunk = k >> 8, within = k & 255;
    const int step = within >> 4, l15 = within & 15;
#pragma unroll
    for (int l4 = 0; l4 < 4; ++l4) {
        half8 h, lo;
#pragma unroll
        for (int j = 0; j < 8; ++j) {
            float x = v[l4 * 8 + j];
            _Float16 hh = (_Float16)x;
            h[j]  = hh;
            lo[j] = (_Float16)(x - (float)hh);
        }
        const int slot = chunk * 1024 + step * 64 + l4 * 16 + l15;
        *reinterpret_cast<half8*>(Eh + (size_t)slot * 8) = h;
        *reinterpret_cast<half8*>(El + (size_t)slot * 8) = lo;
    }
}

// ---------------- main: R5-proven MFMA argmax + POOLED parallel exact rescore ----------
// 1024 blocks x 256 thr; wave owns 32 tokens (m=2); 4 chunks x 256 codes; LDS ~34.5 KB.
// Tail: block-wide flag pooling -> flagged tokens split round-robin across the 4 waves
// (kills straggler-wave serialization); threshold tightened to 2g+eps (sound; see notes).
__global__ __launch_bounds__(256) void vq_main(
    const float* __restrict__ w, const float* __restrict__ c,
    const float* __restrict__ nhb, const _Float16* __restrict__ Eh,
    const _Float16* __restrict__ El, const float* __restrict__ cbT,
    int* __restrict__ out)
{
    __shared__ _Float16 sEh[1024 * 8];   // 16 KB
    __shared__ _Float16 sEl[1024 * 8];   // 16 KB
    __shared__ float    snh[CCODES];     // 1 KB
    __shared__ int      sOut[128];       // 512 B
    __shared__ float    sXf[4][DIM];     // 512 B per-wave rescore scratch

    const int tid  = threadIdx.x;
    const int lane = tid & 63;
    const int wid  = tid >> 6;
    const int tok0 = blockIdx.x * 128;
    const int tokw = tok0 + wid * 32;    // 32 tokens per wave
    const int l15  = lane & 15;
    const int l4   = lane >> 4;

    // A fragments: 2 tiles of 16 tokens. A[row=l15][k=l4*8+j]; exact x = xh + xl
    half8 xh[2], xl[2];
#pragma unroll
    for (int m = 0; m < 2; ++m) {
        const int token = tokw + m * 16 + l15;
        const float4* pw = reinterpret_cast<const float4*>(w + (size_t)token * DIM + l4 * 8);
        const float4* pc = reinterpret_cast<const float4*>(c + (size_t)token * DIM + l4 * 8);
        float4 a0 = pw[0], a1 = pw[1], b0 = pc[0], b1 = pc[1];
        float xs[8] = {a0.x - b0.x, a0.y - b0.y, a0.z - b0.z, a0.w - b0.w,
                       a1.x - b1.x, a1.y - b1.y, a1.z - b1.z, a1.w - b1.w};
#pragma unroll
        for (int j = 0; j < 8; ++j) {
            _Float16 h = (_Float16)xs[j];
            xh[m][j] = h;
            xl[m][j] = (_Float16)(xs[j] - (float)h);
        }
    }

    const float NEGINF = __uint_as_float(0xFF800000u);
    float best[8], second[8];
#pragma unroll
    for (int q = 0; q < 8; ++q) { best[q] = NEGINF; second[q] = NEGINF; }

    for (int ch = 0; ch < 4; ++ch) {
        if (ch) __syncthreads();   // all waves done reading previous chunk before overwrite
        {   // stage 256 codes (hi+lo, 32 KB) + snh (1 KB), all-linear async global->LDS
            const _Float16* gh = Eh + (size_t)ch * 8192;
            const _Float16* gl = El + (size_t)ch * 8192;
#pragma unroll
            for (int r2 = 0; r2 < 4; ++r2) {
                const int slot = r2 * 256 + wid * 64;   // wave-uniform base
                GLOAD_LDS16(gh + (size_t)(slot + lane) * 8, sEh + (size_t)slot * 8);
                GLOAD_LDS16(gl + (size_t)(slot + lane) * 8, sEl + (size_t)slot * 8);
            }
            GLOAD_LDS4(nhb + ch * CCODES + wid * 64 + lane, snh + wid * 64);
        }
        __syncthreads();   // drain -> staged data visible

        // 16 steps of 16 codes, in pairs (med3 second-tracking) -- R5's proven loop
#pragma unroll
        for (int sp = 0; sp < 8; ++sp) {
            const int sA = 2 * sp, sB = 2 * sp + 1;
            const half8 ehA = *reinterpret_cast<const half8*>(sEh + (size_t)(sA * 64 + lane) * 8);
            const half8 elA = *reinterpret_cast<const half8*>(sEl + (size_t)(sA * 64 + lane) * 8);
            const half8 ehB = *reinterpret_cast<const half8*>(sEh + (size_t)(sB * 64 + lane) * 8);
            const half8 elB = *reinterpret_cast<const half8*>(sEl + (size_t)(sB * 64 + lane) * 8);
            const float nhA = snh[sA * 16 + l15];
            const float nhB = snh[sB * 16 + l15];
            const unsigned ixA = 1023u - (unsigned)(ch * CCODES + sA * 16 + l15);
            const unsigned ixB = ixA - 16u;
            const floatx4 nA = {nhA, nhA, nhA, nhA};
            const floatx4 nB = {nhB, nhB, nhB, nhB};
#pragma unroll
            for (int m = 0; m < 2; ++m) {
                floatx4 aA = __builtin_amdgcn_mfma_f32_16x16x32_f16(xh[m], ehA, nA, 0, 0, 0);
                aA = __builtin_amdgcn_mfma_f32_16x16x32_f16(xl[m], ehA, aA, 0, 0, 0);
                aA = __builtin_amdgcn_mfma_f32_16x16x32_f16(xh[m], elA, aA, 0, 0, 0);
                floatx4 aB = __builtin_amdgcn_mfma_f32_16x16x32_f16(xh[m], ehB, nB, 0, 0, 0);
                aB = __builtin_amdgcn_mfma_f32_16x16x32_f16(xl[m], ehB, aB, 0, 0, 0);
                aB = __builtin_amdgcn_mfma_f32_16x16x32_f16(xh[m], elB, aB, 0, 0, 0);
#pragma unroll
                for (int r = 0; r < 4; ++r) {
                    const int q = m * 4 + r;
                    float pA = __uint_as_float((__float_as_uint(aA[r]) & 0xFFFFFC00u) | ixA);
                    float pB = __uint_as_float((__float_as_uint(aB[r]) & 0xFFFFFC00u) | ixB);
                    second[q] = fmaxf(second[q], __builtin_amdgcn_fmed3f(pA, pB, best[q]));
                    best[q]   = fmaxf(fmaxf(best[q], pA), pB);
                }
            }
        }
    }

    // reduce across the 16 code-lanes (xor over lane bits 0..3)
#pragma unroll
    for (int sh = 1; sh < 16; sh <<= 1) {
#pragma unroll
        for (int q = 0; q < 8; ++q) {
            float bB = __shfl_xor(best[q], sh);
            float sB = __shfl_xor(second[q], sh);
            second[q] = fmaxf(fmaxf(second[q], sB), fminf(best[q], bB));
            best[q]   = fmaxf(best[q], bB);
        }
    }

    // stage per-token results (k | optional FLAGBIT); threshold = 2*granule + eps
    // (masking error < g one-sided, packed-index bias < g; unflagged => true approx gap
    //  > g + eps >> 2*eps_mfma ~ 1e-5 at these magnitudes -- sound, 2x fewer flags)
    if (l15 == 0) {
#pragma unroll
        for (int m = 0; m < 2; ++m) {
#pragma unroll
            for (int r = 0; r < 4; ++r) {
                const int q = m * 4 + r;
                unsigned ub = __float_as_uint(best[q]);
                unsigned us = __float_as_uint(second[q]);
                float bv = __uint_as_float(ub & 0xFFFFFC00u);
                float sv = __uint_as_float(us & 0xFFFFFC00u);
                int eb = (int)((ub >> 23) & 255u);
                int es = (int)((us >> 23) & 255u);
                int em = eb > es ? eb : es;
                em = em > 12 ? em : 12;
                float thr = __uint_as_float((unsigned)(em - 12) << 23) + DELTA_EPS;
                int k = 1023 - (int)(ub & 1023u);
                sOut[wid * 32 + m * 16 + l4 * 4 + r] = ((bv - sv) < thr) ? (k | FLAGBIT) : k;
            }
        }
    }
    __syncthreads();   // sOut visible block-wide for pooling

    // ---- pooled tail: bulk-write unflagged; split flagged round-robin across waves
    int v0 = sOut[lane];        // tokens tok0 + 0..63
    int v1 = sOut[64 + lane];   // tokens tok0 + 64..127
    unsigned long long f0 = __ballot((v0 & FLAGBIT) != 0);
    unsigned long long f1 = __ballot((v1 & FLAGBIT) != 0);
    if (!(v0 & FLAGBIT)) out[tok0 + lane]      = v0;
    if (!(v1 & FLAGBIT)) out[tok0 + 64 + lane] = v1;

    int j = 0;
#pragma unroll
    for (int h = 0; h < 2; ++h) {
        unsigned long long m = h ? f1 : f0;
        while (m) {
            const int pos = __ffsll(m) - 1;
            m &= m - 1;
            if ((j++ & 3) != wid) continue;     // this wave's share only
            const int token = tok0 + h * 64 + pos;   // wave-uniform

            if (lane < DIM)
                sXf[wid][lane] = w[(size_t)token * DIM + lane] - c[(size_t)token * DIM + lane];
            // same-wave LDS: in-order, compiler inserts lgkmcnt before reads

            float x2 = 0.f;
#pragma unroll
            for (int i = 0; i < DIM; ++i) x2 = fmaf(sXf[wid][i], sXf[wid][i], x2);

            float dmin = INFINITY;
            int   kbest = 0;
            for (int i = 0; i < 16; ++i) {         // NOT unrolled (R21: unroll -> VGPR 256)
                const int k = lane + 64 * i;       // ascending per lane
                float dot = 0.f;
#pragma unroll
                for (int jj = 0; jj < DIM; ++jj)   // sequential order j=0..31, bit-exact
                    dot = fmaf(sXf[wid][jj], cbT[(size_t)jj * NCODE + k], dot);
                float e2 = -2.0f * nhb[k];         // bit-exact |e|^2 (seq-fma in prep)
                float dd = fmaf(-2.0f, dot, x2) + e2;
                if (dd < dmin) { dmin = dd; kbest = k; }
            }
#pragma unroll
            for (int sh = 1; sh < 64; sh <<= 1) {
                float dB = __shfl_xor(dmin, sh);
                int   iB = __shfl_xor(kbest, sh);
                bool take = (dB < dmin) || (dB == dmin && iB < kbest);
                dmin = take ? dB : dmin;
                kbest = take ? iB : kbest;
            }
            if (lane == 0) out[token] = kbest;     // exact index, sole writer
        }
    }
}

extern "C" void kernel_launch(void* const* d_in, const int* in_sizes, int n_in,
                              void* d_out, int out_size, void* d_ws, size_t ws_size,
                              hipStream_t stream) {
    const float* w  = (const float*)d_in[0];   // weights   [4194304]
    const float* c  = (const float*)d_in[1];   // condition [1,32,131072] flat
    const float* cb = (const float*)d_in[2];   // codebook  [1024,32]
    int* out = (int*)d_out;                    // int32 indices [131072]

    char* wsb = (char*)d_ws;
    float*    nhb = (float*)wsb;                                // 4 KB
    _Float16* Eh  = (_Float16*)(wsb + 4096);                    // 64 KB (fragment-ordered)
    _Float16* El  = (_Float16*)(wsb + 4096 + 65536);            // 64 KB (fragment-ordered)
    float*    cbT = (float*)(wsb + 4096 + 65536 + 65536);       // 128 KB (dim-major)

    vq_prep<<<NCODE / 64, 64, 0, stream>>>(cb, nhb, Eh, El, cbT);
    vq_main<<<NTOK / 128, 256, 0, stream>>>(w, c, nhb, Eh, El, cbT, out);
}

// Round 24
// 50.836 us; speedup vs baseline: 2.3636x; 1.0366x over previous
//
#include <hip/hip_runtime.h>

#define TOTAL     4194304
#define DIM       32
#define NTOK      (TOTAL / DIM)   // 131072 tokens
#define NCODE     1024
#define CCODES    256             // codes per chunk (4 chunks) -- proven R5/R18 geometry
#define DELTA_EPS 2e-3f
#define FLAGBIT   0x40000000

typedef _Float16 half8   __attribute__((ext_vector_type(8)));
typedef float    floatx4 __attribute__((ext_vector_type(4)));

#define GLOAD_LDS16(g, l) \
    __builtin_amdgcn_global_load_lds((const __attribute__((address_space(1))) void*)(g), \
                                     (__attribute__((address_space(3))) void*)(l), 16, 0, 0)
#define GLOAD_LDS4(g, l) \
    __builtin_amdgcn_global_load_lds((const __attribute__((address_space(1))) void*)(g), \
                                     (__attribute__((address_space(3))) void*)(l), 4, 0, 0)

// ---------------- prep: codebook -> f16 hi/lo fragments + (-0.5*|e|^2) + TRANSPOSE ------
__global__ __launch_bounds__(64) void vq_prep(
    const float* __restrict__ cb, float* __restrict__ nhb,
    _Float16* __restrict__ Eh, _Float16* __restrict__ El,
    float* __restrict__ cbT)
{
    const int k = blockIdx.x * 64 + threadIdx.x;   // code id
    const float4* e4 = reinterpret_cast<const float4*>(cb) + (size_t)k * 8;
    float v[DIM];
    float4 t[8];
#pragma unroll
    for (int j = 0; j < 8; ++j) t[j] = e4[j];
#pragma unroll
    for (int j = 0; j < 8; ++j) {
        v[4 * j + 0] = t[j].x; v[4 * j + 1] = t[j].y;
        v[4 * j + 2] = t[j].z; v[4 * j + 3] = t[j].w;
    }
    float e2 = 0.0f;
#pragma unroll
    for (int i = 0; i < DIM; ++i) e2 = fmaf(v[i], v[i], e2);   // sequential: matches rescore
    nhb[k] = -0.5f * e2;

    // transpose: for fixed j, lanes write consecutive k -> coalesced stores
#pragma unroll
    for (int j = 0; j < DIM; ++j) cbT[(size_t)j * NCODE + k] = v[j];

    const int chunk = k >> 8, within = k & 255;
    const int step = within >> 4, l15 = within & 15;
#pragma unroll
    for (int l4 = 0; l4 < 4; ++l4) {
        half8 h, lo;
#pragma unroll
        for (int j = 0; j < 8; ++j) {
            float x = v[l4 * 8 + j];
            _Float16 hh = (_Float16)x;
            h[j]  = hh;
            lo[j] = (_Float16)(x - (float)hh);
        }
        const int slot = chunk * 1024 + step * 64 + l4 * 16 + l15;
        *reinterpret_cast<half8*>(Eh + (size_t)slot * 8) = h;
        *reinterpret_cast<half8*>(El + (size_t)slot * 8) = lo;
    }
}

// ---------------- main: R5-proven MFMA argmax + pooled exact rescore, VGPR pinned ------
// 1024 blocks x 256 thr; wave owns 32 tokens (m=2); 4 chunks x 256 codes; LDS ~34.5 KB.
// amdgpu_num_vgpr(60): main loop provably fits in 60 (R20); keeps the kernel under the
// vgpr=64 wave-budget cliff (m69). Any forced spill lands in the ~0.2%-executed tail.
__global__ __launch_bounds__(256) __attribute__((amdgpu_num_vgpr(60))) void vq_main(
    const float* __restrict__ w, const float* __restrict__ c,
    const float* __restrict__ nhb, const _Float16* __restrict__ Eh,
    const _Float16* __restrict__ El, const float* __restrict__ cbT,
    int* __restrict__ out)
{
    __shared__ _Float16 sEh[1024 * 8];   // 16 KB
    __shared__ _Float16 sEl[1024 * 8];   // 16 KB
    __shared__ float    snh[CCODES];     // 1 KB
    __shared__ int      sOut[128];       // 512 B
    __shared__ float    sXf[4][DIM];     // 512 B per-wave rescore scratch

    const int tid  = threadIdx.x;
    const int lane = tid & 63;
    const int wid  = tid >> 6;
    const int tok0 = blockIdx.x * 128;
    const int tokw = tok0 + wid * 32;    // 32 tokens per wave
    const int l15  = lane & 15;
    const int l4   = lane >> 4;

    // A fragments: 2 tiles of 16 tokens. A[row=l15][k=l4*8+j]; exact x = xh + xl
    half8 xh[2], xl[2];
#pragma unroll
    for (int m = 0; m < 2; ++m) {
        const int token = tokw + m * 16 + l15;
        const float4* pw = reinterpret_cast<const float4*>(w + (size_t)token * DIM + l4 * 8);
        const float4* pc = reinterpret_cast<const float4*>(c + (size_t)token * DIM + l4 * 8);
        float4 a0 = pw[0], a1 = pw[1], b0 = pc[0], b1 = pc[1];
        float xs[8] = {a0.x - b0.x, a0.y - b0.y, a0.z - b0.z, a0.w - b0.w,
                       a1.x - b1.x, a1.y - b1.y, a1.z - b1.z, a1.w - b1.w};
#pragma unroll
        for (int j = 0; j < 8; ++j) {
            _Float16 h = (_Float16)xs[j];
            xh[m][j] = h;
            xl[m][j] = (_Float16)(xs[j] - (float)h);
        }
    }

    const float NEGINF = __uint_as_float(0xFF800000u);
    float best[8], second[8];
#pragma unroll
    for (int q = 0; q < 8; ++q) { best[q] = NEGINF; second[q] = NEGINF; }

    for (int ch = 0; ch < 4; ++ch) {
        if (ch) __syncthreads();   // all waves done reading previous chunk before overwrite
        {   // stage 256 codes (hi+lo, 32 KB) + snh (1 KB), all-linear async global->LDS
            const _Float16* gh = Eh + (size_t)ch * 8192;
            const _Float16* gl = El + (size_t)ch * 8192;
#pragma unroll
            for (int r2 = 0; r2 < 4; ++r2) {
                const int slot = r2 * 256 + wid * 64;   // wave-uniform base
                GLOAD_LDS16(gh + (size_t)(slot + lane) * 8, sEh + (size_t)slot * 8);
                GLOAD_LDS16(gl + (size_t)(slot + lane) * 8, sEl + (size_t)slot * 8);
            }
            GLOAD_LDS4(nhb + ch * CCODES + wid * 64 + lane, snh + wid * 64);
        }
        __syncthreads();   // drain -> staged data visible

        // 16 steps of 16 codes, in pairs (med3 second-tracking) -- R5's proven loop
#pragma unroll
        for (int sp = 0; sp < 8; ++sp) {
            const int sA = 2 * sp, sB = 2 * sp + 1;
            const half8 ehA = *reinterpret_cast<const half8*>(sEh + (size_t)(sA * 64 + lane) * 8);
            const half8 elA = *reinterpret_cast<const half8*>(sEl + (size_t)(sA * 64 + lane) * 8);
            const half8 ehB = *reinterpret_cast<const half8*>(sEh + (size_t)(sB * 64 + lane) * 8);
            const half8 elB = *reinterpret_cast<const half8*>(sEl + (size_t)(sB * 64 + lane) * 8);
            const float nhA = snh[sA * 16 + l15];
            const float nhB = snh[sB * 16 + l15];
            const unsigned ixA = 1023u - (unsigned)(ch * CCODES + sA * 16 + l15);
            const unsigned ixB = ixA - 16u;
            const floatx4 nA = {nhA, nhA, nhA, nhA};
            const floatx4 nB = {nhB, nhB, nhB, nhB};
#pragma unroll
            for (int m = 0; m < 2; ++m) {
                floatx4 aA = __builtin_amdgcn_mfma_f32_16x16x32_f16(xh[m], ehA, nA, 0, 0, 0);
                aA = __builtin_amdgcn_mfma_f32_16x16x32_f16(xl[m], ehA, aA, 0, 0, 0);
                aA = __builtin_amdgcn_mfma_f32_16x16x32_f16(xh[m], elA, aA, 0, 0, 0);
                floatx4 aB = __builtin_amdgcn_mfma_f32_16x16x32_f16(xh[m], ehB, nB, 0, 0, 0);
                aB = __builtin_amdgcn_mfma_f32_16x16x32_f16(xl[m], ehB, aB, 0, 0, 0);
                aB = __builtin_amdgcn_mfma_f32_16x16x32_f16(xh[m], elB, aB, 0, 0, 0);
#pragma unroll
                for (int r = 0; r < 4; ++r) {
                    const int q = m * 4 + r;
                    float pA = __uint_as_float((__float_as_uint(aA[r]) & 0xFFFFFC00u) | ixA);
                    float pB = __uint_as_float((__float_as_uint(aB[r]) & 0xFFFFFC00u) | ixB);
                    second[q] = fmaxf(second[q], __builtin_amdgcn_fmed3f(pA, pB, best[q]));
                    best[q]   = fmaxf(fmaxf(best[q], pA), pB);
                }
            }
        }
    }

    // reduce across the 16 code-lanes (xor over lane bits 0..3)
#pragma unroll
    for (int sh = 1; sh < 16; sh <<= 1) {
#pragma unroll
        for (int q = 0; q < 8; ++q) {
            float bB = __shfl_xor(best[q], sh);
            float sB = __shfl_xor(second[q], sh);
            second[q] = fmaxf(fmaxf(second[q], sB), fminf(best[q], bB));
            best[q]   = fmaxf(best[q], bB);
        }
    }

    // stage per-token results (k | optional FLAGBIT); threshold = 2*granule + eps
    if (l15 == 0) {
#pragma unroll
        for (int m = 0; m < 2; ++m) {
#pragma unroll
            for (int r = 0; r < 4; ++r) {
                const int q = m * 4 + r;
                unsigned ub = __float_as_uint(best[q]);
                unsigned us = __float_as_uint(second[q]);
                float bv = __uint_as_float(ub & 0xFFFFFC00u);
                float sv = __uint_as_float(us & 0xFFFFFC00u);
                int eb = (int)((ub >> 23) & 255u);
                int es = (int)((us >> 23) & 255u);
                int em = eb > es ? eb : es;
                em = em > 12 ? em : 12;
                float thr = __uint_as_float((unsigned)(em - 12) << 23) + DELTA_EPS;
                int k = 1023 - (int)(ub & 1023u);
                sOut[wid * 32 + m * 16 + l4 * 4 + r] = ((bv - sv) < thr) ? (k | FLAGBIT) : k;
            }
        }
    }
    __syncthreads();   // sOut visible block-wide for pooling

    // ---- pooled tail: bulk-write unflagged; split flagged round-robin across waves
    int v0 = sOut[lane];        // tokens tok0 + 0..63
    int v1 = sOut[64 + lane];   // tokens tok0 + 64..127
    unsigned long long f0 = __ballot((v0 & FLAGBIT) != 0);
    unsigned long long f1 = __ballot((v1 & FLAGBIT) != 0);
    if (!(v0 & FLAGBIT)) out[tok0 + lane]      = v0;
    if (!(v1 & FLAGBIT)) out[tok0 + 64 + lane] = v1;

    int j = 0;
#pragma unroll
    for (int h = 0; h < 2; ++h) {
        unsigned long long m = h ? f1 : f0;
        while (m) {
            const int pos = __ffsll(m) - 1;
            m &= m - 1;
            if ((j++ & 3) != wid) continue;     // this wave's share only
            const int token = tok0 + h * 64 + pos;   // wave-uniform

            if (lane < DIM)
                sXf[wid][lane] = w[(size_t)token * DIM + lane] - c[(size_t)token * DIM + lane];
            // same-wave LDS: in-order, compiler inserts lgkmcnt before reads

            float x2 = 0.f;
#pragma unroll
            for (int i = 0; i < DIM; ++i) x2 = fmaf(sXf[wid][i], sXf[wid][i], x2);

            float dmin = INFINITY;
            int   kbest = 0;
            for (int i = 0; i < 16; ++i) {         // NOT unrolled (R21: unroll -> VGPR 256)
                const int k = lane + 64 * i;       // ascending per lane
                float dot = 0.f;
#pragma unroll
                for (int jj = 0; jj < DIM; ++jj)   // sequential order j=0..31, bit-exact
                    dot = fmaf(sXf[wid][jj], cbT[(size_t)jj * NCODE + k], dot);
                float e2 = -2.0f * nhb[k];         // bit-exact |e|^2 (seq-fma in prep)
                float dd = fmaf(-2.0f, dot, x2) + e2;
                if (dd < dmin) { dmin = dd; kbest = k; }
            }
#pragma unroll
            for (int sh = 1; sh < 64; sh <<= 1) {
                float dB = __shfl_xor(dmin, sh);
                int   iB = __shfl_xor(kbest, sh);
                bool take = (dB < dmin) || (dB == dmin && iB < kbest);
                dmin = take ? dB : dmin;
                kbest = take ? iB : kbest;
            }
            if (lane == 0) out[token] = kbest;     // exact index, sole writer
        }
    }
}

extern "C" void kernel_launch(void* const* d_in, const int* in_sizes, int n_in,
                              void* d_out, int out_size, void* d_ws, size_t ws_size,
                              hipStream_t stream) {
    const float* w  = (const float*)d_in[0];   // weights   [4194304]
    const float* c  = (const float*)d_in[1];   // condition [1,32,131072] flat
    const float* cb = (const float*)d_in[2];   // codebook  [1024,32]
    int* out = (int*)d_out;                    // int32 indices [131072]

    char* wsb = (char*)d_ws;
    float*    nhb = (float*)wsb;                                // 4 KB
    _Float16* Eh  = (_Float16*)(wsb + 4096);                    // 64 KB (fragment-ordered)
    _Float16* El  = (_Float16*)(wsb + 4096 + 65536);            // 64 KB (fragment-ordered)
    float*    cbT = (float*)(wsb + 4096 + 65536 + 65536);       // 128 KB (dim-major)

    vq_prep<<<NCODE / 64, 64, 0, stream>>>(cb, nhb, Eh, El, cbT);
    vq_main<<<NTOK / 128, 256, 0, stream>>>(w, c, nhb, Eh, El, cbT, out);
}